// Round 1
// baseline (988.881 us; speedup 1.0000x reference)
//
#include <hip/hip_runtime.h>
#include <math.h>

#define NN 50000
#define NR 2000
#define NT 1000000
#define HID 128
#define OSTRIDE 768

__device__ __forceinline__ float wsum(float v) {
#pragma unroll
  for (int off = 32; off > 0; off >>= 1) v += __shfl_xor(v, off, 64);
  return v;
}
__device__ __forceinline__ float wmax(float v) {
#pragma unroll
  for (int off = 32; off > 0; off >>= 1) v = fmaxf(v, __shfl_xor(v, off, 64));
  return v;
}

// Build CSR row pointers from sorted, covering row array.
__global__ void rowptr_kernel(const int* __restrict__ rows, int* __restrict__ rp,
                              int T, int N) {
  int i = blockIdx.x * blockDim.x + threadIdx.x;
  int stride = gridDim.x * blockDim.x;
  for (int t = i; t < T; t += stride) {
    if (t == 0 || rows[t] != rows[t - 1]) rp[rows[t]] = t;
  }
  if (i == 0) rp[N] = T;
}

// Per-relation: norm of rel_emb row, and dot with each of the 4 attention kernels.
__global__ __launch_bounds__(256) void relpre_kernel(
    const float* __restrict__ rel_emb, const float* __restrict__ attn_e,
    const float* __restrict__ attn_r, float* __restrict__ norm_rel,
    float* __restrict__ attdot) {
  int wid = (blockIdx.x * blockDim.x + threadIdx.x) >> 6;
  int lane = threadIdx.x & 63;
  if (wid >= NR) return;
  const float2* e2 = (const float2*)rel_emb;
  float2 e = e2[(size_t)wid * 64 + lane];
  float p = e.x * e.x + e.y * e.y;
  p = wsum(p);
  if (lane == 0) norm_rel[wid] = sqrtf(p);
  const float* ks[4] = {attn_e, attn_e + HID, attn_r, attn_r + HID};
#pragma unroll
  for (int j = 0; j < 4; ++j) {
    float2 a = ((const float2*)ks[j])[lane];
    float d = e.x * a.x + e.y * a.y;
    d = wsum(d);
    if (lane == 0) attdot[wid * 4 + j] = d;
  }
}

// Segment mean + tanh, wave per node, dim-per-lane (float2).
__global__ __launch_bounds__(256) void avg_tanh_kernel(
    const int* __restrict__ rp, const int* __restrict__ cols,
    const float* __restrict__ emb, float* __restrict__ out /* d_out + col off */) {
  int wid = (blockIdx.x * blockDim.x + threadIdx.x) >> 6;
  int lane = threadIdx.x & 63;
  if (wid >= NN) return;
  int t0 = rp[wid], t1 = rp[wid + 1];
  float2 acc = make_float2(0.f, 0.f);
  const float2* emb2 = (const float2*)emb;
  for (int t = t0; t < t1; ++t) {
    float2 v = emb2[(size_t)cols[t] * 64 + lane];
    acc.x += v.x;
    acc.y += v.y;
  }
  float invd = 1.f / (float)(t1 - t0);  // deg >= 1 (covering)
  float* o = out + (size_t)wid * OSTRIDE + 2 * lane;
  o[0] = tanhf(acc.x * invd);
  o[1] = tanhf(acc.y * invd);
}

// One attention layer for both branches. Wave per (branch, node).
__global__ __launch_bounds__(256) void attn_kernel(
    float* __restrict__ feats_base,   // d_out
    const int* __restrict__ src_rp,   // [NN+1]
    const int* __restrict__ dst,      // adj[1]
    const int* __restrict__ rel_id,   // r_index[1]
    const float* __restrict__ r_val,
    const float* __restrict__ rel_emb,
    const float* __restrict__ norm_rel,
    const float* __restrict__ attdot,  // [NR][4]
    int layer) {
  int wid = (blockIdx.x * blockDim.x + threadIdx.x) >> 6;
  int lane = threadIdx.x & 63;
  if (wid >= 2 * NN) return;
  int branch = (wid >= NN) ? 1 : 0;
  int n = wid - branch * NN;
  int lb = branch * 2 + layer;
  const float* fin = feats_base + (size_t)(branch * 3 + layer) * HID;
  float* fout = feats_base + (size_t)(branch * 3 + layer + 1) * HID;

  int t0 = src_rp[n], t1 = src_rp[n + 1];

  // pass 1: segment max of att (lane-parallel over triples)
  float m = -INFINITY;
  for (int t = t0 + lane; t < t1; t += 64) {
    int r = rel_id[t];
    float rv = r_val[t];
    float scale = rv / fmaxf(rv * norm_rel[r], 1e-12f);
    m = fmaxf(m, scale * attdot[r * 4 + lb]);
  }
  m = wmax(m);

  // pass 2: sum of exp
  float s = 0.f;
  for (int t = t0 + lane; t < t1; t += 64) {
    int r = rel_id[t];
    float rv = r_val[t];
    float scale = rv / fmaxf(rv * norm_rel[r], 1e-12f);
    s += expf(scale * attdot[r * 4 + lb] - m);
  }
  s = wsum(s);
  float inv_s = 1.f / s;

  // pass 3: weighted Householder-reflected neighbor accumulation
  float2 acc = make_float2(0.f, 0.f);
  const float2* remb2 = (const float2*)rel_emb;
  for (int t = t0; t < t1; ++t) {
    int r = rel_id[t];
    float rv = r_val[t];
    float scale = rv / fmaxf(rv * norm_rel[r], 1e-12f);
    float w = expf(scale * attdot[r * 4 + lb] - m) * inv_s;
    float2 u = remb2[(size_t)r * 64 + lane];
    u.x *= scale;
    u.y *= scale;
    int dn = dst[t];
    const float2 nb = *(const float2*)(fin + (size_t)dn * OSTRIDE + 2 * lane);
    float d = nb.x * u.x + nb.y * u.y;
    d = wsum(d);
    float c = -2.f * d * w;
    acc.x += w * nb.x + c * u.x;
    acc.y += w * nb.y + c * u.y;
  }
  float* o = fout + (size_t)n * OSTRIDE + 2 * lane;
  o[0] = tanhf(acc.x);
  o[1] = tanhf(acc.y);
}

extern "C" void kernel_launch(void* const* d_in, const int* in_sizes, int n_in,
                              void* d_out, int out_size, void* d_ws, size_t ws_size,
                              hipStream_t stream) {
  const float* ent_emb = (const float*)d_in[0];
  const float* rel_emb = (const float*)d_in[1];
  const float* attn_e = (const float*)d_in[2];
  const float* attn_r = (const float*)d_in[3];
  const int* adj = (const int*)d_in[4];
  const int* r_index = (const int*)d_in[5];
  const float* r_val = (const float*)d_in[6];
  const int* ent_adj = (const int*)d_in[7];
  const int* rel_adj = (const int*)d_in[8];
  float* out = (float*)d_out;

  char* ws = (char*)d_ws;
  int* rp_adj = (int*)ws;   ws += (NN + 1) * sizeof(int);
  int* rp_ent = (int*)ws;   ws += (NN + 1) * sizeof(int);
  int* rp_rel = (int*)ws;   ws += (NN + 1) * sizeof(int);
  float* norm_rel = (float*)ws; ws += NR * sizeof(float);
  float* attdot = (float*)ws;   ws += NR * 4 * sizeof(float);

  rowptr_kernel<<<512, 256, 0, stream>>>(adj, rp_adj, NT, NN);
  rowptr_kernel<<<512, 256, 0, stream>>>(ent_adj, rp_ent, NT, NN);
  rowptr_kernel<<<512, 256, 0, stream>>>(rel_adj, rp_rel, NT, NN);
  relpre_kernel<<<(NR * 64 + 255) / 256, 256, 0, stream>>>(
      rel_emb, attn_e, attn_r, norm_rel, attdot);

  // layer-0 features (tanh of segment means) written straight into d_out
  avg_tanh_kernel<<<(NN * 64 + 255) / 256, 256, 0, stream>>>(
      rp_ent, ent_adj + NT, ent_emb, out + 0 * HID);          // ent branch, col 0
  avg_tanh_kernel<<<(NN * 64 + 255) / 256, 256, 0, stream>>>(
      rp_rel, rel_adj + NT, rel_emb, out + 3 * HID);          // rel branch, col 384

  for (int l = 0; l < 2; ++l) {
    attn_kernel<<<(2 * NN * 64 + 255) / 256, 256, 0, stream>>>(
        out, rp_adj, adj + NT, r_index + NT, r_val, rel_emb, norm_rel, attdot, l);
  }
}

// Round 2
// 664.520 us; speedup vs baseline: 1.4881x; 1.4881x over previous
//
#include <hip/hip_runtime.h>
#include <math.h>

#define NN 50000
#define NR 2000
#define NT 1000000
#define HID 128
#define OSTRIDE 768

__device__ __forceinline__ float wsum64(float v) {
#pragma unroll
  for (int off = 32; off > 0; off >>= 1) v += __shfl_xor(v, off, 64);
  return v;
}

// ---------- row pointers for all three sorted covering adjacencies ----------
__global__ void rowptr3_kernel(const int* __restrict__ a0, int* __restrict__ r0,
                               const int* __restrict__ a1, int* __restrict__ r1,
                               const int* __restrict__ a2, int* __restrict__ r2) {
  const int* rows = (blockIdx.y == 0) ? a0 : (blockIdx.y == 1) ? a1 : a2;
  int* rp = (blockIdx.y == 0) ? r0 : (blockIdx.y == 1) ? r1 : r2;
  int i = blockIdx.x * blockDim.x + threadIdx.x;
  int stride = gridDim.x * blockDim.x;
  for (int t = i; t < NT; t += stride) {
    if (t == 0 || rows[t] != rows[t - 1]) rp[rows[t]] = t;
  }
  if (i == 0) rp[NN] = NT;
}

// ---------- per-relation: norm and dots with the 4 attention kernels ----------
__global__ __launch_bounds__(256) void relpre_kernel(
    const float* __restrict__ rel_emb, const float* __restrict__ attn_e,
    const float* __restrict__ attn_r, float* __restrict__ norm_rel,
    float* __restrict__ attdot) {
  int wid = (blockIdx.x * blockDim.x + threadIdx.x) >> 6;
  int lane = threadIdx.x & 63;
  if (wid >= NR) return;
  const float2* e2 = (const float2*)rel_emb;
  float2 e = e2[(size_t)wid * 64 + lane];
  float p = wsum64(e.x * e.x + e.y * e.y);
  if (lane == 0) norm_rel[wid] = sqrtf(p);
  const float* ks[4] = {attn_e, attn_e + HID, attn_r, attn_r + HID};
#pragma unroll
  for (int j = 0; j < 4; ++j) {
    float2 a = ((const float2*)ks[j])[lane];
    float d = wsum64(e.x * a.x + e.y * a.y);
    if (lane == 0) attdot[wid * 4 + j] = d;
  }
}

// ---------- precompute per-triple softmax weights (all 4 branch/layer) + scale^2 ----------
__global__ __launch_bounds__(256) void wpre_kernel(
    const int* __restrict__ rp, const int* __restrict__ rel_id,
    const float* __restrict__ r_val, const float* __restrict__ norm_rel,
    const float* __restrict__ attdot,  // [NR] float4
    float4* __restrict__ w4, float* __restrict__ s2) {
  int wid = (blockIdx.x * blockDim.x + threadIdx.x) >> 6;
  int lane = threadIdx.x & 63;
  if (wid >= NN) return;
  int t0 = rp[wid], t1 = rp[wid + 1];
  const float4* ad4 = (const float4*)attdot;

  float4 m = make_float4(-INFINITY, -INFINITY, -INFINITY, -INFINITY);
  for (int t = t0 + lane; t < t1; t += 64) {
    int r = rel_id[t];
    float rv = r_val[t];
    float sc = rv / fmaxf(rv * norm_rel[r], 1e-12f);
    float4 a = ad4[r];
    m.x = fmaxf(m.x, sc * a.x); m.y = fmaxf(m.y, sc * a.y);
    m.z = fmaxf(m.z, sc * a.z); m.w = fmaxf(m.w, sc * a.w);
  }
#pragma unroll
  for (int off = 32; off > 0; off >>= 1) {
    m.x = fmaxf(m.x, __shfl_xor(m.x, off, 64));
    m.y = fmaxf(m.y, __shfl_xor(m.y, off, 64));
    m.z = fmaxf(m.z, __shfl_xor(m.z, off, 64));
    m.w = fmaxf(m.w, __shfl_xor(m.w, off, 64));
  }
  float4 s = make_float4(0.f, 0.f, 0.f, 0.f);
  for (int t = t0 + lane; t < t1; t += 64) {
    int r = rel_id[t];
    float rv = r_val[t];
    float sc = rv / fmaxf(rv * norm_rel[r], 1e-12f);
    float4 a = ad4[r];
    s.x += expf(sc * a.x - m.x); s.y += expf(sc * a.y - m.y);
    s.z += expf(sc * a.z - m.z); s.w += expf(sc * a.w - m.w);
  }
  s.x = wsum64(s.x); s.y = wsum64(s.y); s.z = wsum64(s.z); s.w = wsum64(s.w);
  float4 inv = make_float4(1.f / s.x, 1.f / s.y, 1.f / s.z, 1.f / s.w);
  for (int t = t0 + lane; t < t1; t += 64) {
    int r = rel_id[t];
    float rv = r_val[t];
    float sc = rv / fmaxf(rv * norm_rel[r], 1e-12f);
    float4 a = ad4[r];
    float4 w;
    w.x = expf(sc * a.x - m.x) * inv.x;
    w.y = expf(sc * a.y - m.y) * inv.y;
    w.z = expf(sc * a.z - m.z) * inv.z;
    w.w = expf(sc * a.w - m.w) * inv.w;
    w4[t] = w;
    s2[t] = sc * sc;
  }
}

// ---------- layer-0: segment mean + tanh for both branches (2 nodes / wave) ----------
__global__ __launch_bounds__(256) void avg_tanh_kernel(
    const int* __restrict__ rp_ent, const int* __restrict__ cols_ent,
    const float* __restrict__ ent_emb, const int* __restrict__ rp_rel,
    const int* __restrict__ cols_rel, const float* __restrict__ rel_emb,
    float* __restrict__ out) {
  int wid = (blockIdx.x * blockDim.x + threadIdx.x) >> 6;
  int lane = threadIdx.x & 63;
  if (wid >= NN) return;  // 25000 pairs per branch
  int br = (wid >= NN / 2) ? 1 : 0;
  int pair = wid - br * (NN / 2);
  int node = pair * 2 + (lane >> 5);
  int sl = lane & 31;
  const int* rp = br ? rp_rel : rp_ent;
  const int* cols = br ? cols_rel : cols_ent;
  const float* emb = br ? rel_emb : ent_emb;
  int outcol = br ? 3 * HID : 0;
  int t0 = rp[node], t1 = rp[node + 1];
  float4 acc = make_float4(0.f, 0.f, 0.f, 0.f);
  for (int t = t0; t < t1; ++t) {
    int c = cols[t];
    const float4 v = *(const float4*)(emb + (size_t)c * HID + sl * 4);
    acc.x += v.x; acc.y += v.y; acc.z += v.z; acc.w += v.w;
  }
  float inv = 1.f / (float)(t1 - t0);
  float4 o;
  o.x = tanhf(acc.x * inv); o.y = tanhf(acc.y * inv);
  o.z = tanhf(acc.z * inv); o.w = tanhf(acc.w * inv);
  *(float4*)(out + (size_t)node * OSTRIDE + outcol + sl * 4) = o;
}

__device__ __forceinline__ void fma_acc(float4& a, float w, const float4& nb,
                                        float c, const float4& u) {
  a.x += w * nb.x + c * u.x;
  a.y += w * nb.y + c * u.y;
  a.z += w * nb.z + c * u.z;
  a.w += w * nb.w + c * u.w;
}
__device__ __forceinline__ float4 comb4(float4 a) {
  a.x += __shfl_xor(a.x, 16, 64); a.y += __shfl_xor(a.y, 16, 64);
  a.z += __shfl_xor(a.z, 16, 64); a.w += __shfl_xor(a.w, 16, 64);
  a.x += __shfl_xor(a.x, 32, 64); a.y += __shfl_xor(a.y, 32, 64);
  a.z += __shfl_xor(a.z, 32, 64); a.w += __shfl_xor(a.w, 32, 64);
  return a;
}

// ---------- one attention layer, both branches fused; 4 triples per wave iter ----------
__global__ __launch_bounds__(256) void attn_kernel(
    float* __restrict__ out, const int* __restrict__ rp,
    const int* __restrict__ dst, const float* __restrict__ rel_emb,
    const int* __restrict__ rel_id, const float4* __restrict__ w4,
    const float* __restrict__ s2, int layer) {
  int wid = (blockIdx.x * blockDim.x + threadIdx.x) >> 6;
  int lane = threadIdx.x & 63;
  if (wid >= NN) return;
  int g = lane >> 4;    // triple slot 0..3
  int sl = lane & 15;   // dim slot: dims [sl*8, sl*8+8)
  const float* fin_e = out + layer * HID;
  const float* fin_r = out + (3 + layer) * HID;

  int t0 = rp[wid], t1 = rp[wid + 1];
  float4 ae0 = make_float4(0, 0, 0, 0), ae1 = ae0, ar0 = ae0, ar1 = ae0;

  for (int tb = t0; tb < t1; tb += 4) {
    int t = tb + g;
    bool valid = (t < t1);
    int tc = valid ? t : (t1 - 1);
    int dn = dst[tc];
    int r = rel_id[tc];
    float4 w = w4[tc];
    float sc2 = s2[tc];
    float we = (layer == 0) ? w.x : w.y;
    float wr = (layer == 0) ? w.z : w.w;
    if (!valid) { we = 0.f; wr = 0.f; }

    const float4* up = (const float4*)(rel_emb + r * HID + sl * 8);
    float4 u0 = up[0], u1 = up[1];
    const float4* pe = (const float4*)(fin_e + (size_t)dn * OSTRIDE + sl * 8);
    float4 e0 = pe[0], e1 = pe[1];
    const float4* pr = (const float4*)(fin_r + (size_t)dn * OSTRIDE + sl * 8);
    float4 q0 = pr[0], q1 = pr[1];

    float de = u0.x * e0.x + u0.y * e0.y + u0.z * e0.z + u0.w * e0.w +
               u1.x * e1.x + u1.y * e1.y + u1.z * e1.z + u1.w * e1.w;
    float dr = u0.x * q0.x + u0.y * q0.y + u0.z * q0.z + u0.w * q0.w +
               u1.x * q1.x + u1.y * q1.y + u1.z * q1.z + u1.w * q1.w;
#pragma unroll
    for (int off = 1; off < 16; off <<= 1) {
      de += __shfl_xor(de, off, 64);
      dr += __shfl_xor(dr, off, 64);
    }
    float ce = -2.f * we * sc2 * de;
    float cr = -2.f * wr * sc2 * dr;
    fma_acc(ae0, we, e0, ce, u0);
    fma_acc(ae1, we, e1, ce, u1);
    fma_acc(ar0, wr, q0, cr, u0);
    fma_acc(ar1, wr, q1, cr, u1);
  }

  ae0 = comb4(ae0); ae1 = comb4(ae1); ar0 = comb4(ar0); ar1 = comb4(ar1);

  float4 v;
  if (g == 0) v = ae0;
  else if (g == 1) v = ae1;
  else if (g == 2) v = ar0;
  else v = ar1;
  v.x = tanhf(v.x); v.y = tanhf(v.y); v.z = tanhf(v.z); v.w = tanhf(v.w);
  float* ob = (g < 2) ? (out + (size_t)wid * OSTRIDE + (layer + 1) * HID)
                      : (out + (size_t)wid * OSTRIDE + (4 + layer) * HID);
  *(float4*)(ob + sl * 8 + (g & 1) * 4) = v;
}

extern "C" void kernel_launch(void* const* d_in, const int* in_sizes, int n_in,
                              void* d_out, int out_size, void* d_ws, size_t ws_size,
                              hipStream_t stream) {
  const float* ent_emb = (const float*)d_in[0];
  const float* rel_emb = (const float*)d_in[1];
  const float* attn_e = (const float*)d_in[2];
  const float* attn_r = (const float*)d_in[3];
  const int* adj = (const int*)d_in[4];
  const int* r_index = (const int*)d_in[5];
  const float* r_val = (const float*)d_in[6];
  const int* ent_adj = (const int*)d_in[7];
  const int* rel_adj = (const int*)d_in[8];
  float* out = (float*)d_out;

  char* ws = (char*)d_ws;
  float4* w4 = (float4*)ws;        ws += (size_t)NT * sizeof(float4);  // 16 MB
  float* s2 = (float*)ws;          ws += (size_t)NT * sizeof(float);   // 4 MB
  float* attdot = (float*)ws;      ws += (size_t)NR * 4 * sizeof(float);
  float* norm_rel = (float*)ws;    ws += (size_t)NR * sizeof(float);
  int* rp_adj = (int*)ws;          ws += (NN + 1) * sizeof(int);
  int* rp_ent = (int*)ws;          ws += (NN + 1) * sizeof(int);
  int* rp_rel = (int*)ws;          ws += (NN + 1) * sizeof(int);

  dim3 rg(512, 3);
  rowptr3_kernel<<<rg, 256, 0, stream>>>(adj, rp_adj, ent_adj, rp_ent, rel_adj, rp_rel);
  relpre_kernel<<<(NR * 64) / 256, 256, 0, stream>>>(rel_emb, attn_e, attn_r,
                                                     norm_rel, attdot);
  wpre_kernel<<<(NN * 64) / 256, 256, 0, stream>>>(rp_adj, r_index + NT, r_val,
                                                   norm_rel, attdot, w4, s2);
  avg_tanh_kernel<<<(NN * 64) / 256, 256, 0, stream>>>(
      rp_ent, ent_adj + NT, ent_emb, rp_rel, rel_adj + NT, rel_emb, out);
  for (int l = 0; l < 2; ++l) {
    attn_kernel<<<(NN * 64) / 256, 256, 0, stream>>>(
        out, rp_adj, adj + NT, rel_emb, r_index + NT, w4, s2, l);
  }
}

// Round 3
// 637.539 us; speedup vs baseline: 1.5511x; 1.0423x over previous
//
#include <hip/hip_runtime.h>
#include <math.h>

#define NN 50000
#define NR 2000
#define NT 1000000
#define HID 128
#define OSTRIDE 768

__device__ __forceinline__ float wsum64(float v) {
#pragma unroll
  for (int off = 32; off > 0; off >>= 1) v += __shfl_xor(v, off, 64);
  return v;
}

// ---------- row pointers for all three sorted covering adjacencies ----------
__global__ void rowptr3_kernel(const int* __restrict__ a0, int* __restrict__ r0,
                               const int* __restrict__ a1, int* __restrict__ r1,
                               const int* __restrict__ a2, int* __restrict__ r2) {
  const int* rows = (blockIdx.y == 0) ? a0 : (blockIdx.y == 1) ? a1 : a2;
  int* rp = (blockIdx.y == 0) ? r0 : (blockIdx.y == 1) ? r1 : r2;
  int i = blockIdx.x * blockDim.x + threadIdx.x;
  int stride = gridDim.x * blockDim.x;
  for (int t = i; t < NT; t += stride) {
    if (t == 0 || rows[t] != rows[t - 1]) rp[rows[t]] = t;
  }
  if (i == 0) rp[NN] = NT;
}

// ---------- per-relation: norm and dots with the 4 attention kernels ----------
__global__ __launch_bounds__(256) void relpre_kernel(
    const float* __restrict__ rel_emb, const float* __restrict__ attn_e,
    const float* __restrict__ attn_r, float* __restrict__ norm_rel,
    float* __restrict__ attdot) {
  int wid = (blockIdx.x * blockDim.x + threadIdx.x) >> 6;
  int lane = threadIdx.x & 63;
  if (wid >= NR) return;
  const float2* e2 = (const float2*)rel_emb;
  float2 e = e2[(size_t)wid * 64 + lane];
  float p = wsum64(e.x * e.x + e.y * e.y);
  if (lane == 0) norm_rel[wid] = sqrtf(p);
  const float* ks[4] = {attn_e, attn_e + HID, attn_r, attn_r + HID};
#pragma unroll
  for (int j = 0; j < 4; ++j) {
    float2 a = ((const float2*)ks[j])[lane];
    float d = wsum64(e.x * a.x + e.y * a.y);
    if (lane == 0) attdot[wid * 4 + j] = d;
  }
}

// ---------- per-triple softmax weights; 2 passes (att is bounded, no max needed;
// softmax is shift-invariant so result is identical) ----------
__global__ __launch_bounds__(256) void wpre_kernel(
    const int* __restrict__ rp, const int* __restrict__ rel_id,
    const float* __restrict__ r_val, const float* __restrict__ norm_rel,
    const float* __restrict__ attdot,  // [NR] float4
    float2* __restrict__ wl0, float2* __restrict__ wl1, float* __restrict__ s2) {
  int wid = (blockIdx.x * blockDim.x + threadIdx.x) >> 6;
  int lane = threadIdx.x & 63;
  if (wid >= NN) return;
  int t0 = rp[wid], t1 = rp[wid + 1];
  const float4* ad4 = (const float4*)attdot;

  float4 s = make_float4(0.f, 0.f, 0.f, 0.f);
  for (int t = t0 + lane; t < t1; t += 64) {
    int r = rel_id[t];
    float rv = r_val[t];
    float sc = rv / fmaxf(rv * norm_rel[r], 1e-12f);
    float4 a = ad4[r];
    s.x += expf(sc * a.x); s.y += expf(sc * a.y);
    s.z += expf(sc * a.z); s.w += expf(sc * a.w);
  }
  s.x = wsum64(s.x); s.y = wsum64(s.y); s.z = wsum64(s.z); s.w = wsum64(s.w);
  float4 inv = make_float4(1.f / s.x, 1.f / s.y, 1.f / s.z, 1.f / s.w);
  for (int t = t0 + lane; t < t1; t += 64) {
    int r = rel_id[t];
    float rv = r_val[t];
    float sc = rv / fmaxf(rv * norm_rel[r], 1e-12f);
    float4 a = ad4[r];
    wl0[t] = make_float2(expf(sc * a.x) * inv.x, expf(sc * a.z) * inv.z);
    wl1[t] = make_float2(expf(sc * a.y) * inv.y, expf(sc * a.w) * inv.w);
    s2[t] = sc * sc;
  }
}

// ---------- layer-0: segment mean + tanh, 2 nodes/wave, 2 rows/iter, col prefetch ----------
__global__ __launch_bounds__(256) void avg_tanh_kernel(
    const int* __restrict__ rp_ent, const int* __restrict__ cols_ent,
    const float* __restrict__ ent_emb, const int* __restrict__ rp_rel,
    const int* __restrict__ cols_rel, const float* __restrict__ rel_emb,
    float* __restrict__ out) {
  int wid = (blockIdx.x * blockDim.x + threadIdx.x) >> 6;
  int lane = threadIdx.x & 63;
  if (wid >= NN) return;  // 25000 node-pairs per branch
  int br = (wid >= NN / 2) ? 1 : 0;
  int pair = wid - br * (NN / 2);
  int node = pair * 2 + (lane >> 5);
  int sl = lane & 31;
  const int* rp = br ? rp_rel : rp_ent;
  const int* cols = br ? cols_rel : cols_ent;
  const float* emb = br ? rel_emb : ent_emb;
  int outcol = br ? 3 * HID : 0;
  int t0 = rp[node], t1 = rp[node + 1];
  int nmax = t1 - 1;
  int c0 = cols[t0];
  int c1 = cols[min(t0 + 1, nmax)];
  float4 a0 = make_float4(0.f, 0.f, 0.f, 0.f), a1 = a0;
  for (int t = t0; t < t1; t += 2) {
    const float4 v0 = *(const float4*)(emb + (size_t)c0 * HID + sl * 4);
    const float4 v1 = *(const float4*)(emb + (size_t)c1 * HID + sl * 4);
    int tn = t + 2;
    c0 = cols[min(tn, nmax)];
    c1 = cols[min(tn + 1, nmax)];
    a0.x += v0.x; a0.y += v0.y; a0.z += v0.z; a0.w += v0.w;
    float m1 = (t + 1 < t1) ? 1.f : 0.f;
    a1.x += m1 * v1.x; a1.y += m1 * v1.y; a1.z += m1 * v1.z; a1.w += m1 * v1.w;
  }
  float inv = 1.f / (float)(t1 - t0);
  float4 o;
  o.x = tanhf((a0.x + a1.x) * inv); o.y = tanhf((a0.y + a1.y) * inv);
  o.z = tanhf((a0.z + a1.z) * inv); o.w = tanhf((a0.w + a1.w) * inv);
  *(float4*)(out + (size_t)node * OSTRIDE + outcol + sl * 4) = o;
}

struct BlkT { int dn; int r; float we, wr, s2; };

__device__ __forceinline__ BlkT ldblk(int tb, int g, int t1,
                                      const int* __restrict__ dst,
                                      const int* __restrict__ rel_id,
                                      const float2* __restrict__ wl,
                                      const float* __restrict__ s2p) {
  int t = tb + g;
  bool valid = (t < t1);
  int tc = valid ? t : (t1 - 1);
  BlkT b;
  b.dn = dst[tc];
  b.r = rel_id[tc];
  float2 w = wl[tc];
  b.we = valid ? w.x : 0.f;
  b.wr = valid ? w.y : 0.f;
  b.s2 = s2p[tc];
  return b;
}

__device__ __forceinline__ float dot8(const float4& a, const float4& b,
                                      const float4& c, const float4& d) {
  return a.x * c.x + a.y * c.y + a.z * c.z + a.w * c.w +
         b.x * d.x + b.y * d.y + b.z * d.z + b.w * d.w;
}
__device__ __forceinline__ void fma_acc(float4& a, float w, const float4& nb,
                                        float c, const float4& u) {
  a.x += w * nb.x + c * u.x;
  a.y += w * nb.y + c * u.y;
  a.z += w * nb.z + c * u.z;
  a.w += w * nb.w + c * u.w;
}
__device__ __forceinline__ float4 comb4(float4 a) {
  a.x += __shfl_xor(a.x, 16, 64); a.y += __shfl_xor(a.y, 16, 64);
  a.z += __shfl_xor(a.z, 16, 64); a.w += __shfl_xor(a.w, 16, 64);
  a.x += __shfl_xor(a.x, 32, 64); a.y += __shfl_xor(a.y, 32, 64);
  a.z += __shfl_xor(a.z, 32, 64); a.w += __shfl_xor(a.w, 32, 64);
  return a;
}

// ---------- one attention layer, both branches fused; 4 triples/iter,
// indices for next block prefetched one iteration ahead ----------
__global__ __launch_bounds__(256) void attn_kernel(
    float* __restrict__ out, const int* __restrict__ rp,
    const int* __restrict__ dst, const float* __restrict__ rel_emb,
    const int* __restrict__ rel_id, const float2* __restrict__ wl,
    const float* __restrict__ s2p, int layer) {
  int wid = (blockIdx.x * blockDim.x + threadIdx.x) >> 6;
  int lane = threadIdx.x & 63;
  if (wid >= NN) return;
  int g = lane >> 4;   // triple slot 0..3
  int sl = lane & 15;  // dims [sl*8, sl*8+8)
  const float* fin_e = out + layer * HID;
  const float* fin_r = out + (3 + layer) * HID;

  int t0 = rp[wid], t1 = rp[wid + 1];
  BlkT b0 = ldblk(t0, g, t1, dst, rel_id, wl, s2p);
  float4 ae0 = make_float4(0, 0, 0, 0), ae1 = ae0, ar0 = ae0, ar1 = ae0;

  for (int tb = t0; tb < t1; tb += 4) {
    // issue current block's gathers (addresses already resident)
    const float4* up = (const float4*)(rel_emb + b0.r * HID + sl * 8);
    float4 u0 = up[0], u1 = up[1];
    const float4* pe = (const float4*)(fin_e + (size_t)b0.dn * OSTRIDE + sl * 8);
    float4 e0 = pe[0], e1 = pe[1];
    const float4* pr = (const float4*)(fin_r + (size_t)b0.dn * OSTRIDE + sl * 8);
    float4 q0 = pr[0], q1 = pr[1];
    // prefetch next block's indices/weights under the gather latency
    BlkT b1 = ldblk(tb + 4, g, t1, dst, rel_id, wl, s2p);

    float de = dot8(u0, u1, e0, e1);
    float dr = dot8(u0, u1, q0, q1);
#pragma unroll
    for (int off = 1; off < 16; off <<= 1) {
      de += __shfl_xor(de, off, 64);
      dr += __shfl_xor(dr, off, 64);
    }
    float ce = -2.f * b0.we * b0.s2 * de;
    float cr = -2.f * b0.wr * b0.s2 * dr;
    fma_acc(ae0, b0.we, e0, ce, u0);
    fma_acc(ae1, b0.we, e1, ce, u1);
    fma_acc(ar0, b0.wr, q0, cr, u0);
    fma_acc(ar1, b0.wr, q1, cr, u1);
    b0 = b1;
  }

  ae0 = comb4(ae0); ae1 = comb4(ae1); ar0 = comb4(ar0); ar1 = comb4(ar1);

  float4 v;
  if (g == 0) v = ae0;
  else if (g == 1) v = ae1;
  else if (g == 2) v = ar0;
  else v = ar1;
  v.x = tanhf(v.x); v.y = tanhf(v.y); v.z = tanhf(v.z); v.w = tanhf(v.w);
  float* ob = (g < 2) ? (out + (size_t)wid * OSTRIDE + (layer + 1) * HID)
                      : (out + (size_t)wid * OSTRIDE + (4 + layer) * HID);
  *(float4*)(ob + sl * 8 + (g & 1) * 4) = v;
}

extern "C" void kernel_launch(void* const* d_in, const int* in_sizes, int n_in,
                              void* d_out, int out_size, void* d_ws, size_t ws_size,
                              hipStream_t stream) {
  const float* ent_emb = (const float*)d_in[0];
  const float* rel_emb = (const float*)d_in[1];
  const float* attn_e = (const float*)d_in[2];
  const float* attn_r = (const float*)d_in[3];
  const int* adj = (const int*)d_in[4];
  const int* r_index = (const int*)d_in[5];
  const float* r_val = (const float*)d_in[6];
  const int* ent_adj = (const int*)d_in[7];
  const int* rel_adj = (const int*)d_in[8];
  float* out = (float*)d_out;

  char* ws = (char*)d_ws;
  float2* wl0 = (float2*)ws;    ws += (size_t)NT * sizeof(float2);  // 8 MB
  float2* wl1 = (float2*)ws;    ws += (size_t)NT * sizeof(float2);  // 8 MB
  float* s2 = (float*)ws;       ws += (size_t)NT * sizeof(float);   // 4 MB
  float* attdot = (float*)ws;   ws += (size_t)NR * 4 * sizeof(float);
  float* norm_rel = (float*)ws; ws += (size_t)NR * sizeof(float);
  int* rp_adj = (int*)ws;       ws += (NN + 1) * sizeof(int);
  int* rp_ent = (int*)ws;       ws += (NN + 1) * sizeof(int);
  int* rp_rel = (int*)ws;       ws += (NN + 1) * sizeof(int);

  dim3 rg(512, 3);
  rowptr3_kernel<<<rg, 256, 0, stream>>>(adj, rp_adj, ent_adj, rp_ent, rel_adj, rp_rel);
  relpre_kernel<<<(NR * 64) / 256, 256, 0, stream>>>(rel_emb, attn_e, attn_r,
                                                     norm_rel, attdot);
  wpre_kernel<<<(NN * 64) / 256, 256, 0, stream>>>(rp_adj, r_index + NT, r_val,
                                                   norm_rel, attdot, wl0, wl1, s2);
  avg_tanh_kernel<<<(NN * 64) / 256, 256, 0, stream>>>(
      rp_ent, ent_adj + NT, ent_emb, rp_rel, rel_adj + NT, rel_emb, out);
  for (int l = 0; l < 2; ++l) {
    attn_kernel<<<(NN * 64) / 256, 256, 0, stream>>>(
        out, rp_adj, adj + NT, rel_emb, r_index + NT, l == 0 ? wl0 : wl1, s2, l);
  }
}

// Round 4
// 627.761 us; speedup vs baseline: 1.5753x; 1.0156x over previous
//
#include <hip/hip_runtime.h>
#include <math.h>

#define NN 50000
#define NR 2000
#define NT 1000000
#define HID 128
#define OSTRIDE 768
#define CSTRIDE 256

__device__ __forceinline__ float wsum64(float v) {
#pragma unroll
  for (int off = 32; off > 0; off >>= 1) v += __shfl_xor(v, off, 64);
  return v;
}

// ---------- row pointers for all three sorted covering adjacencies ----------
__global__ void rowptr3_kernel(const int* __restrict__ a0, int* __restrict__ r0,
                               const int* __restrict__ a1, int* __restrict__ r1,
                               const int* __restrict__ a2, int* __restrict__ r2) {
  const int* rows = (blockIdx.y == 0) ? a0 : (blockIdx.y == 1) ? a1 : a2;
  int* rp = (blockIdx.y == 0) ? r0 : (blockIdx.y == 1) ? r1 : r2;
  int i = blockIdx.x * blockDim.x + threadIdx.x;
  int stride = gridDim.x * blockDim.x;
  for (int t = i; t < NT; t += stride) {
    if (t == 0 || rows[t] != rows[t - 1]) rp[rows[t]] = t;
  }
  if (i == 0) rp[NN] = NT;
}

// ---------- per-relation tables: exp(attdot/norm) for 4 kernels + 1/norm^2 ----------
__global__ __launch_bounds__(256) void relpre_kernel(
    const float* __restrict__ rel_emb, const float* __restrict__ attn_e,
    const float* __restrict__ attn_r, float4* __restrict__ e4,
    float4* __restrict__ tab0, float4* __restrict__ tab1) {
  int wid = (blockIdx.x * blockDim.x + threadIdx.x) >> 6;
  int lane = threadIdx.x & 63;
  if (wid >= NR) return;
  const float2* e2 = (const float2*)rel_emb;
  float2 e = e2[(size_t)wid * 64 + lane];
  float p = wsum64(e.x * e.x + e.y * e.y);  // norm^2
  float inv_n = rsqrtf(p);
  float n2i = 1.f / p;
  const float* ks[4] = {attn_e, attn_e + HID, attn_r, attn_r + HID};
  float d[4];
#pragma unroll
  for (int j = 0; j < 4; ++j) {
    float2 a = ((const float2*)ks[j])[lane];
    d[j] = wsum64(e.x * a.x + e.y * a.y);
  }
  if (lane == 0) {
    float4 ex = make_float4(expf(d[0] * inv_n), expf(d[1] * inv_n),
                            expf(d[2] * inv_n), expf(d[3] * inv_n));
    e4[wid] = ex;
    tab0[wid] = make_float4(ex.x, ex.z, n2i, 0.f);  // layer 0: (e, r, s2)
    tab1[wid] = make_float4(ex.y, ex.w, n2i, 0.f);  // layer 1
  }
}

// ---------- per-node softmax denominators (one pass, no per-triple writes) ----------
__global__ __launch_bounds__(256) void wpre_kernel(
    const int* __restrict__ rp, const int* __restrict__ rel_id,
    const float* __restrict__ r_val, const float4* __restrict__ e4,
    float4* __restrict__ Sinv4) {
  int wid = (blockIdx.x * blockDim.x + threadIdx.x) >> 6;
  int lane = threadIdx.x & 63;
  if (wid >= NN) return;
  int t0 = rp[wid], t1 = rp[wid + 1];
  float4 s = make_float4(0.f, 0.f, 0.f, 0.f);
  for (int t = t0 + lane; t < t1; t += 64) {
    int r = rel_id[t];
    float rv = r_val[t];
    float4 ex = e4[r];
    if (rv <= 0.f) ex = make_float4(1.f, 1.f, 1.f, 1.f);  // exp(0)
    s.x += ex.x; s.y += ex.y; s.z += ex.z; s.w += ex.w;
  }
  s.x = wsum64(s.x); s.y = wsum64(s.y); s.z = wsum64(s.z); s.w = wsum64(s.w);
  if (lane == 0)
    Sinv4[wid] = make_float4(1.f / s.x, 1.f / s.y, 1.f / s.z, 1.f / s.w);
}

// ---------- layer-0: segment mean + tanh, 2 nodes/wave, 4 rows in flight ----------
__global__ __launch_bounds__(256) void avg_tanh_kernel(
    const int* __restrict__ rp_ent, const int* __restrict__ cols_ent,
    const float* __restrict__ ent_emb, const int* __restrict__ rp_rel,
    const int* __restrict__ cols_rel, const float* __restrict__ rel_emb,
    float* __restrict__ out, float* __restrict__ c0buf) {
  int wid = (blockIdx.x * blockDim.x + threadIdx.x) >> 6;
  int lane = threadIdx.x & 63;
  if (wid >= NN) return;  // 25000 node-pairs per branch
  int br = (wid >= NN / 2) ? 1 : 0;
  int pair = wid - br * (NN / 2);
  int node = pair * 2 + (lane >> 5);
  int sl = lane & 31;
  const int* rp = br ? rp_rel : rp_ent;
  const int* cols = br ? cols_rel : cols_ent;
  const float* emb = br ? rel_emb : ent_emb;
  int t0 = rp[node], t1 = rp[node + 1];
  int nmax = t1 - 1;
  int c0 = cols[t0];
  int c1 = cols[min(t0 + 1, nmax)];
  int c2 = cols[min(t0 + 2, nmax)];
  int c3 = cols[min(t0 + 3, nmax)];
  float4 acc = make_float4(0.f, 0.f, 0.f, 0.f);
  for (int t = t0; t < t1; t += 4) {
    const float4 v0 = *(const float4*)(emb + (size_t)c0 * HID + sl * 4);
    const float4 v1 = *(const float4*)(emb + (size_t)c1 * HID + sl * 4);
    const float4 v2 = *(const float4*)(emb + (size_t)c2 * HID + sl * 4);
    const float4 v3 = *(const float4*)(emb + (size_t)c3 * HID + sl * 4);
    int tn = t + 4;
    c0 = cols[min(tn, nmax)];
    c1 = cols[min(tn + 1, nmax)];
    c2 = cols[min(tn + 2, nmax)];
    c3 = cols[min(tn + 3, nmax)];
    float m1 = (t + 1 < t1) ? 1.f : 0.f;
    float m2 = (t + 2 < t1) ? 1.f : 0.f;
    float m3 = (t + 3 < t1) ? 1.f : 0.f;
    acc.x += v0.x + m1 * v1.x + m2 * v2.x + m3 * v3.x;
    acc.y += v0.y + m1 * v1.y + m2 * v2.y + m3 * v3.y;
    acc.z += v0.z + m1 * v1.z + m2 * v2.z + m3 * v3.z;
    acc.w += v0.w + m1 * v1.w + m2 * v2.w + m3 * v3.w;
  }
  float inv = 1.f / (float)(t1 - t0);
  float4 o;
  o.x = tanhf(acc.x * inv); o.y = tanhf(acc.y * inv);
  o.z = tanhf(acc.z * inv); o.w = tanhf(acc.w * inv);
  *(float4*)(out + (size_t)node * OSTRIDE + (br ? 3 * HID : 0) + sl * 4) = o;
  if (c0buf)
    *(float4*)(c0buf + (size_t)node * CSTRIDE + br * HID + sl * 4) = o;
}

struct BlkT { int dn; int r; float tx, ty, n2i; };

__device__ __forceinline__ BlkT ldblk(int tb, int g, int t1,
                                      const int* __restrict__ dst,
                                      const int* __restrict__ rel_id,
                                      const float* __restrict__ r_val,
                                      const float4* __restrict__ tab) {
  int t = tb + g;
  bool valid = (t < t1);
  int tc = valid ? t : (t1 - 1);
  BlkT b;
  b.dn = dst[tc];
  b.r = rel_id[tc];
  float rv = r_val[tc];
  float4 tv = tab[b.r];
  if (rv <= 0.f) tv = make_float4(1.f, 1.f, 0.f, 0.f);  // zero-scale triple
  b.tx = valid ? tv.x : 0.f;
  b.ty = valid ? tv.y : 0.f;
  b.n2i = tv.z;
  return b;
}

__device__ __forceinline__ float dot8(const float4& a, const float4& b,
                                      const float4& c, const float4& d) {
  return a.x * c.x + a.y * c.y + a.z * c.z + a.w * c.w +
         b.x * d.x + b.y * d.y + b.z * d.z + b.w * d.w;
}
__device__ __forceinline__ void fma_acc(float4& a, float w, const float4& nb,
                                        float c, const float4& u) {
  a.x += w * nb.x + c * u.x;
  a.y += w * nb.y + c * u.y;
  a.z += w * nb.z + c * u.z;
  a.w += w * nb.w + c * u.w;
}
__device__ __forceinline__ float4 comb4(float4 a) {
  a.x += __shfl_xor(a.x, 16, 64); a.y += __shfl_xor(a.y, 16, 64);
  a.z += __shfl_xor(a.z, 16, 64); a.w += __shfl_xor(a.w, 16, 64);
  a.x += __shfl_xor(a.x, 32, 64); a.y += __shfl_xor(a.y, 32, 64);
  a.z += __shfl_xor(a.z, 32, 64); a.w += __shfl_xor(a.w, 32, 64);
  return a;
}

// ---------- one attention layer, both branches fused; 4 triples/iter ----------
__global__ __launch_bounds__(256) void attn_kernel(
    float* __restrict__ out, const int* __restrict__ rp,
    const int* __restrict__ dst, const int* __restrict__ rel_id,
    const float* __restrict__ r_val, const float* __restrict__ rel_emb,
    const float4* __restrict__ tab, const float4* __restrict__ Sinv4,
    const float* __restrict__ gbase, int gstride, int roff,
    float* __restrict__ wc, int layer) {
  int wid = (blockIdx.x * blockDim.x + threadIdx.x) >> 6;
  int lane = threadIdx.x & 63;
  if (wid >= NN) return;
  int g = lane >> 4;   // triple slot 0..3
  int sl = lane & 15;  // dims [sl*8, sl*8+8)

  float4 sv = Sinv4[wid];
  float sie = layer ? sv.y : sv.x;
  float sir = layer ? sv.w : sv.z;

  int t0 = rp[wid], t1 = rp[wid + 1];
  BlkT b0 = ldblk(t0, g, t1, dst, rel_id, r_val, tab);
  float4 ae0 = make_float4(0, 0, 0, 0), ae1 = ae0, ar0 = ae0, ar1 = ae0;

  for (int tb = t0; tb < t1; tb += 4) {
    const float4* up = (const float4*)(rel_emb + b0.r * HID + sl * 8);
    float4 u0 = up[0], u1 = up[1];
    const float* fer = gbase + (size_t)b0.dn * gstride;
    const float4* pe = (const float4*)(fer + sl * 8);
    float4 e0 = pe[0], e1 = pe[1];
    const float4* pr = (const float4*)(fer + roff + sl * 8);
    float4 q0 = pr[0], q1 = pr[1];
    BlkT b1 = ldblk(tb + 4, g, t1, dst, rel_id, r_val, tab);

    float de = dot8(u0, u1, e0, e1);
    float dr = dot8(u0, u1, q0, q1);
#pragma unroll
    for (int off = 1; off < 16; off <<= 1) {
      de += __shfl_xor(de, off, 64);
      dr += __shfl_xor(dr, off, 64);
    }
    float we = b0.tx * sie;
    float wr = b0.ty * sir;
    float ce = -2.f * we * b0.n2i * de;
    float cr = -2.f * wr * b0.n2i * dr;
    fma_acc(ae0, we, e0, ce, u0);
    fma_acc(ae1, we, e1, ce, u1);
    fma_acc(ar0, wr, q0, cr, u0);
    fma_acc(ar1, wr, q1, cr, u1);
    b0 = b1;
  }

  ae0 = comb4(ae0); ae1 = comb4(ae1); ar0 = comb4(ar0); ar1 = comb4(ar1);

  float4 v;
  if (g == 0) v = ae0;
  else if (g == 1) v = ae1;
  else if (g == 2) v = ar0;
  else v = ar1;
  v.x = tanhf(v.x); v.y = tanhf(v.y); v.z = tanhf(v.z); v.w = tanhf(v.w);
  float* ob = (g < 2) ? (out + (size_t)wid * OSTRIDE + (layer + 1) * HID)
                      : (out + (size_t)wid * OSTRIDE + (4 + layer) * HID);
  *(float4*)(ob + sl * 8 + (g & 1) * 4) = v;
  if (wc)
    *(float4*)(wc + (size_t)wid * CSTRIDE + (g >> 1) * HID + sl * 8 +
               (g & 1) * 4) = v;
}

extern "C" void kernel_launch(void* const* d_in, const int* in_sizes, int n_in,
                              void* d_out, int out_size, void* d_ws, size_t ws_size,
                              hipStream_t stream) {
  const float* ent_emb = (const float*)d_in[0];
  const float* rel_emb = (const float*)d_in[1];
  const float* attn_e = (const float*)d_in[2];
  const float* attn_r = (const float*)d_in[3];
  const int* adj = (const int*)d_in[4];
  const int* r_index = (const int*)d_in[5];
  const float* r_val = (const float*)d_in[6];
  const int* ent_adj = (const int*)d_in[7];
  const int* rel_adj = (const int*)d_in[8];
  float* out = (float*)d_out;

  const size_t cbytes = (size_t)NN * CSTRIDE * sizeof(float);  // 51.2 MB
  const size_t small = (size_t)NR * 3 * sizeof(float4) + (size_t)NN * sizeof(float4) +
                       3 * (NN + 1) * sizeof(int) + 1024;
  bool compact = ws_size >= 2 * cbytes + small;

  char* ws = (char*)d_ws;
  float* C0 = nullptr;
  float* C1 = nullptr;
  if (compact) {
    C0 = (float*)ws; ws += cbytes;
    C1 = (float*)ws; ws += cbytes;
  }
  float4* e4 = (float4*)ws;    ws += (size_t)NR * sizeof(float4);
  float4* tab0 = (float4*)ws;  ws += (size_t)NR * sizeof(float4);
  float4* tab1 = (float4*)ws;  ws += (size_t)NR * sizeof(float4);
  float4* Sinv4 = (float4*)ws; ws += (size_t)NN * sizeof(float4);
  int* rp_adj = (int*)ws;      ws += (NN + 1) * sizeof(int);
  int* rp_ent = (int*)ws;      ws += (NN + 1) * sizeof(int);
  int* rp_rel = (int*)ws;      ws += (NN + 1) * sizeof(int);

  dim3 rg(512, 3);
  rowptr3_kernel<<<rg, 256, 0, stream>>>(adj, rp_adj, ent_adj, rp_ent, rel_adj, rp_rel);
  relpre_kernel<<<(NR * 64) / 256, 256, 0, stream>>>(rel_emb, attn_e, attn_r,
                                                     e4, tab0, tab1);
  wpre_kernel<<<(NN * 64) / 256, 256, 0, stream>>>(rp_adj, r_index + NT, r_val,
                                                   e4, Sinv4);
  avg_tanh_kernel<<<(NN * 64) / 256, 256, 0, stream>>>(
      rp_ent, ent_adj + NT, ent_emb, rp_rel, rel_adj + NT, rel_emb, out, C0);

  for (int l = 0; l < 2; ++l) {
    const float* gbase; int gstride, roff;
    if (compact) {
      gbase = (l == 0) ? C0 : C1; gstride = CSTRIDE; roff = HID;
    } else {
      gbase = out + l * HID; gstride = OSTRIDE; roff = 3 * HID;
    }
    float* wc = (compact && l == 0) ? C1 : nullptr;
    attn_kernel<<<(NN * 64) / 256, 256, 0, stream>>>(
        out, rp_adj, adj + NT, r_index + NT, r_val, rel_emb,
        (l == 0) ? tab0 : tab1, Sinv4, gbase, gstride, roff, wc, l);
  }
}

// Round 5
// 474.822 us; speedup vs baseline: 2.0826x; 1.3221x over previous
//
#include <hip/hip_runtime.h>
#include <hip/hip_fp16.h>
#include <math.h>

#define NN 50000
#define NR 2000
#define NT 1000000
#define HID 128
#define OSTRIDE 768
#define CH 256  // halves per compact feature row (e:0..127, r:128..255)

typedef float f32x4 __attribute__((ext_vector_type(4)));
typedef unsigned u32x4 __attribute__((ext_vector_type(4)));
typedef unsigned u32x2 __attribute__((ext_vector_type(2)));

__device__ __forceinline__ float wsum64(float v) {
#pragma unroll
  for (int off = 32; off > 0; off >>= 1) v += __shfl_xor(v, off, 64);
  return v;
}
__device__ __forceinline__ unsigned pack2(float x, float y) {
  __half2 h = __floats2half2_rn(x, y);
  union { __half2 h; unsigned u; } c; c.h = h; return c.u;
}
__device__ __forceinline__ float2 unpack2(unsigned u) {
  union { unsigned u; __half2 h; } c; c.u = u;
  return __half22float2(c.h);
}
__device__ __forceinline__ void nt_store4(const float4& v, float* p) {
  f32x4 t = {v.x, v.y, v.z, v.w};
  __builtin_nontemporal_store(t, (f32x4*)p);
}

// ---------- row pointers for all three sorted covering adjacencies ----------
__global__ void rowptr3_kernel(const int* __restrict__ a0, int* __restrict__ r0,
                               const int* __restrict__ a1, int* __restrict__ r1,
                               const int* __restrict__ a2, int* __restrict__ r2) {
  const int* rows = (blockIdx.y == 0) ? a0 : (blockIdx.y == 1) ? a1 : a2;
  int* rp = (blockIdx.y == 0) ? r0 : (blockIdx.y == 1) ? r1 : r2;
  int i = blockIdx.x * blockDim.x + threadIdx.x;
  int stride = gridDim.x * blockDim.x;
  for (int t = i; t < NT; t += stride) {
    if (t == 0 || rows[t] != rows[t - 1]) rp[rows[t]] = t;
  }
  if (i == 0) rp[NN] = NT;
}

// ---------- per-relation tables ----------
__global__ __launch_bounds__(256) void relpre_kernel(
    const float* __restrict__ rel_emb, const float* __restrict__ attn_e,
    const float* __restrict__ attn_r, float4* __restrict__ e4,
    float4* __restrict__ tab0, float4* __restrict__ tab1) {
  int wid = (blockIdx.x * blockDim.x + threadIdx.x) >> 6;
  int lane = threadIdx.x & 63;
  if (wid >= NR) return;
  const float2* e2 = (const float2*)rel_emb;
  float2 e = e2[(size_t)wid * 64 + lane];
  float p = wsum64(e.x * e.x + e.y * e.y);  // norm^2
  float inv_n = rsqrtf(p);
  float n2i = 1.f / p;
  const float* ks[4] = {attn_e, attn_e + HID, attn_r, attn_r + HID};
  float d[4];
#pragma unroll
  for (int j = 0; j < 4; ++j) {
    float2 a = ((const float2*)ks[j])[lane];
    d[j] = wsum64(e.x * a.x + e.y * a.y);
  }
  if (lane == 0) {
    float4 ex = make_float4(expf(d[0] * inv_n), expf(d[1] * inv_n),
                            expf(d[2] * inv_n), expf(d[3] * inv_n));
    e4[wid] = ex;
    tab0[wid] = make_float4(ex.x, ex.z, n2i, 0.f);  // layer 0: (e, r, s2)
    tab1[wid] = make_float4(ex.y, ex.w, n2i, 0.f);  // layer 1
  }
}

// ---------- f32 -> fp16 mirror of ent_emb ----------
__global__ __launch_bounds__(256) void cvt_kernel(const float* __restrict__ src,
                                                  __half* __restrict__ dh) {
  int i = blockIdx.x * blockDim.x + threadIdx.x;  // NN*HID/8 threads
  const float4* s4 = (const float4*)src;
  float4 a = s4[2 * i], b = s4[2 * i + 1];
  u32x4 w;
  w.x = pack2(a.x, a.y); w.y = pack2(a.z, a.w);
  w.z = pack2(b.x, b.y); w.w = pack2(b.z, b.w);
  __builtin_nontemporal_store(w, (u32x4*)dh + i);
}

// ---------- layer-0: segment mean + tanh, 2 nodes/wave, 4 rows in flight ----------
__global__ __launch_bounds__(256) void avg_tanh_kernel(
    const int* __restrict__ rp_ent, const int* __restrict__ cols_ent,
    const __half* __restrict__ enth, const int* __restrict__ rp_rel,
    const int* __restrict__ cols_rel, const float* __restrict__ rel_emb,
    float* __restrict__ out, __half* __restrict__ c0h) {
  int wid = (blockIdx.x * blockDim.x + threadIdx.x) >> 6;
  int lane = threadIdx.x & 63;
  if (wid >= NN) return;  // 25000 node-pairs per branch
  int br = (wid >= NN / 2) ? 1 : 0;
  int pair = wid - br * (NN / 2);
  int node = pair * 2 + (lane >> 5);
  int sl = lane & 31;
  const int* rp = br ? rp_rel : rp_ent;
  const int* cols = br ? cols_rel : cols_ent;
  int t0 = rp[node], t1 = rp[node + 1];
  int nmax = t1 - 1;
  int c0 = cols[t0];
  int c1 = cols[min(t0 + 1, nmax)];
  int c2 = cols[min(t0 + 2, nmax)];
  int c3 = cols[min(t0 + 3, nmax)];
  float4 acc = make_float4(0.f, 0.f, 0.f, 0.f);
  if (br == 0) {  // ent branch: fp16 mirror gathers (row = 32 x u32x2)
    const u32x2* eb = (const u32x2*)enth;
    for (int t = t0; t < t1; t += 4) {
      u32x2 h0 = eb[(size_t)c0 * 32 + sl];
      u32x2 h1 = eb[(size_t)c1 * 32 + sl];
      u32x2 h2 = eb[(size_t)c2 * 32 + sl];
      u32x2 h3 = eb[(size_t)c3 * 32 + sl];
      int tn = t + 4;
      c0 = cols[min(tn, nmax)];
      c1 = cols[min(tn + 1, nmax)];
      c2 = cols[min(tn + 2, nmax)];
      c3 = cols[min(tn + 3, nmax)];
      float m1 = (t + 1 < t1) ? 1.f : 0.f;
      float m2 = (t + 2 < t1) ? 1.f : 0.f;
      float m3 = (t + 3 < t1) ? 1.f : 0.f;
      float2 a0 = unpack2(h0.x), b0v = unpack2(h0.y);
      float2 a1 = unpack2(h1.x), b1v = unpack2(h1.y);
      float2 a2 = unpack2(h2.x), b2v = unpack2(h2.y);
      float2 a3 = unpack2(h3.x), b3v = unpack2(h3.y);
      acc.x += a0.x + m1 * a1.x + m2 * a2.x + m3 * a3.x;
      acc.y += a0.y + m1 * a1.y + m2 * a2.y + m3 * a3.y;
      acc.z += b0v.x + m1 * b1v.x + m2 * b2v.x + m3 * b3v.x;
      acc.w += b0v.y + m1 * b1v.y + m2 * b2v.y + m3 * b3v.y;
    }
  } else {  // rel branch: f32 gathers from L2-hot 1MB rel_emb
    for (int t = t0; t < t1; t += 4) {
      const float4 v0 = *(const float4*)(rel_emb + (size_t)c0 * HID + sl * 4);
      const float4 v1 = *(const float4*)(rel_emb + (size_t)c1 * HID + sl * 4);
      const float4 v2 = *(const float4*)(rel_emb + (size_t)c2 * HID + sl * 4);
      const float4 v3 = *(const float4*)(rel_emb + (size_t)c3 * HID + sl * 4);
      int tn = t + 4;
      c0 = cols[min(tn, nmax)];
      c1 = cols[min(tn + 1, nmax)];
      c2 = cols[min(tn + 2, nmax)];
      c3 = cols[min(tn + 3, nmax)];
      float m1 = (t + 1 < t1) ? 1.f : 0.f;
      float m2 = (t + 2 < t1) ? 1.f : 0.f;
      float m3 = (t + 3 < t1) ? 1.f : 0.f;
      acc.x += v0.x + m1 * v1.x + m2 * v2.x + m3 * v3.x;
      acc.y += v0.y + m1 * v1.y + m2 * v2.y + m3 * v3.y;
      acc.z += v0.z + m1 * v1.z + m2 * v2.z + m3 * v3.z;
      acc.w += v0.w + m1 * v1.w + m2 * v2.w + m3 * v3.w;
    }
  }
  float inv = 1.f / (float)(t1 - t0);
  float4 o;
  o.x = tanhf(acc.x * inv); o.y = tanhf(acc.y * inv);
  o.z = tanhf(acc.z * inv); o.w = tanhf(acc.w * inv);
  nt_store4(o, out + (size_t)node * OSTRIDE + (br ? 3 * HID : 0) + sl * 4);
  u32x2 w; w.x = pack2(o.x, o.y); w.y = pack2(o.z, o.w);
  __builtin_nontemporal_store(w, (u32x2*)(c0h + (size_t)node * CH + br * HID + sl * 4));
}

struct BlkT { int dn; int r; float tx, ty, n2i; };

__device__ __forceinline__ BlkT ldblk(int tb, int g, int t1,
                                      const int* __restrict__ dst,
                                      const int* __restrict__ rel_id,
                                      const float* __restrict__ r_val,
                                      const float4* __restrict__ tab) {
  int t = tb + g;
  bool valid = (t < t1);
  int tc = valid ? t : (t1 - 1);
  BlkT b;
  b.dn = dst[tc];
  b.r = rel_id[tc];
  float rv = r_val[tc];
  float4 tv = tab[b.r];
  if (rv <= 0.f) tv = make_float4(1.f, 1.f, 0.f, 0.f);  // zero-scale triple
  b.tx = valid ? tv.x : 0.f;
  b.ty = valid ? tv.y : 0.f;
  b.n2i = tv.z;
  return b;
}

__device__ __forceinline__ float dot8(const float4& a, const float4& b,
                                      const float4& c, const float4& d) {
  return a.x * c.x + a.y * c.y + a.z * c.z + a.w * c.w +
         b.x * d.x + b.y * d.y + b.z * d.z + b.w * d.w;
}
__device__ __forceinline__ void fma_acc(float4& a, float w, const float4& nb,
                                        float c, const float4& u) {
  a.x += w * nb.x + c * u.x;
  a.y += w * nb.y + c * u.y;
  a.z += w * nb.z + c * u.z;
  a.w += w * nb.w + c * u.w;
}
__device__ __forceinline__ float4 comb4(float4 a) {
  a.x += __shfl_xor(a.x, 16, 64); a.y += __shfl_xor(a.y, 16, 64);
  a.z += __shfl_xor(a.z, 16, 64); a.w += __shfl_xor(a.w, 16, 64);
  a.x += __shfl_xor(a.x, 32, 64); a.y += __shfl_xor(a.y, 32, 64);
  a.z += __shfl_xor(a.z, 32, 64); a.w += __shfl_xor(a.w, 32, 64);
  return a;
}

// ---------- one attention layer, both branches fused; 4 triples/iter;
// fp16 feature gathers; layer 0 computes its own softmax denominators ----------
__global__ __launch_bounds__(256) void attn_kernel(
    float* __restrict__ out, const int* __restrict__ rp,
    const int* __restrict__ dst, const int* __restrict__ rel_id,
    const float* __restrict__ r_val, const float* __restrict__ rel_emb,
    const float4* __restrict__ tab, const float4* __restrict__ e4,
    float4* __restrict__ Sinv4, const __half* __restrict__ chin,
    __half* __restrict__ chout, int layer) {
  int wid = (blockIdx.x * blockDim.x + threadIdx.x) >> 6;
  int lane = threadIdx.x & 63;
  if (wid >= NN) return;
  int g = lane >> 4;   // triple slot 0..3
  int sl = lane & 15;  // dims [sl*8, sl*8+8)
  int t0 = rp[wid], t1 = rp[wid + 1];

  float sie, sir;
  if (layer == 0) {  // fused softmax-denominator pass (was wpre_kernel)
    float4 s = make_float4(0.f, 0.f, 0.f, 0.f);
    for (int t = t0 + lane; t < t1; t += 64) {
      int r = rel_id[t];
      float rv = r_val[t];
      float4 ex = e4[r];
      if (rv <= 0.f) ex = make_float4(1.f, 1.f, 1.f, 1.f);
      s.x += ex.x; s.y += ex.y; s.z += ex.z; s.w += ex.w;
    }
    s.x = wsum64(s.x); s.y = wsum64(s.y); s.z = wsum64(s.z); s.w = wsum64(s.w);
    float4 inv = make_float4(1.f / s.x, 1.f / s.y, 1.f / s.z, 1.f / s.w);
    if (lane == 0) Sinv4[wid] = inv;
    sie = inv.x; sir = inv.z;
  } else {
    float4 sv = Sinv4[wid];
    sie = sv.y; sir = sv.w;
  }

  BlkT b0 = ldblk(t0, g, t1, dst, rel_id, r_val, tab);
  float4 ae0 = make_float4(0, 0, 0, 0), ae1 = ae0, ar0 = ae0, ar1 = ae0;

  for (int tb = t0; tb < t1; tb += 4) {
    const float4* up = (const float4*)(rel_emb + b0.r * HID + sl * 8);
    float4 u0 = up[0], u1 = up[1];
    const u32x4* ph = (const u32x4*)(chin + (size_t)b0.dn * CH);
    u32x4 eh = ph[sl];
    u32x4 qh = ph[16 + sl];
    BlkT b1 = ldblk(tb + 4, g, t1, dst, rel_id, r_val, tab);

    float2 p0 = unpack2(eh.x), p1 = unpack2(eh.y);
    float2 p2 = unpack2(eh.z), p3 = unpack2(eh.w);
    float4 e0 = make_float4(p0.x, p0.y, p1.x, p1.y);
    float4 e1 = make_float4(p2.x, p2.y, p3.x, p3.y);
    float2 r0v = unpack2(qh.x), r1v = unpack2(qh.y);
    float2 r2v = unpack2(qh.z), r3v = unpack2(qh.w);
    float4 q0 = make_float4(r0v.x, r0v.y, r1v.x, r1v.y);
    float4 q1 = make_float4(r2v.x, r2v.y, r3v.x, r3v.y);

    float de = dot8(u0, u1, e0, e1);
    float dr = dot8(u0, u1, q0, q1);
#pragma unroll
    for (int off = 1; off < 16; off <<= 1) {
      de += __shfl_xor(de, off, 64);
      dr += __shfl_xor(dr, off, 64);
    }
    float we = b0.tx * sie;
    float wr = b0.ty * sir;
    float ce = -2.f * we * b0.n2i * de;
    float cr = -2.f * wr * b0.n2i * dr;
    fma_acc(ae0, we, e0, ce, u0);
    fma_acc(ae1, we, e1, ce, u1);
    fma_acc(ar0, wr, q0, cr, u0);
    fma_acc(ar1, wr, q1, cr, u1);
    b0 = b1;
  }

  ae0 = comb4(ae0); ae1 = comb4(ae1); ar0 = comb4(ar0); ar1 = comb4(ar1);

  float4 v;
  if (g == 0) v = ae0;
  else if (g == 1) v = ae1;
  else if (g == 2) v = ar0;
  else v = ar1;
  v.x = tanhf(v.x); v.y = tanhf(v.y); v.z = tanhf(v.z); v.w = tanhf(v.w);
  float* ob = (g < 2) ? (out + (size_t)wid * OSTRIDE + (layer + 1) * HID)
                      : (out + (size_t)wid * OSTRIDE + (4 + layer) * HID);
  nt_store4(v, ob + sl * 8 + (g & 1) * 4);
  if (chout) {
    u32x2 w; w.x = pack2(v.x, v.y); w.y = pack2(v.z, v.w);
    __builtin_nontemporal_store(
        w, (u32x2*)(chout + (size_t)wid * CH + (g >> 1) * 128 + sl * 8 + (g & 1) * 4));
  }
}

extern "C" void kernel_launch(void* const* d_in, const int* in_sizes, int n_in,
                              void* d_out, int out_size, void* d_ws, size_t ws_size,
                              hipStream_t stream) {
  const float* ent_emb = (const float*)d_in[0];
  const float* rel_emb = (const float*)d_in[1];
  const float* attn_e = (const float*)d_in[2];
  const float* attn_r = (const float*)d_in[3];
  const int* adj = (const int*)d_in[4];
  const int* r_index = (const int*)d_in[5];
  const float* r_val = (const float*)d_in[6];
  const int* ent_adj = (const int*)d_in[7];
  const int* rel_adj = (const int*)d_in[8];
  float* out = (float*)d_out;

  char* ws = (char*)d_ws;
  __half* enth = (__half*)ws;  ws += (size_t)NN * HID * sizeof(__half);  // 12.8 MB
  __half* C0h = (__half*)ws;   ws += (size_t)NN * CH * sizeof(__half);   // 25.6 MB
  __half* C1h = (__half*)ws;   ws += (size_t)NN * CH * sizeof(__half);   // 25.6 MB
  float4* e4 = (float4*)ws;    ws += (size_t)NR * sizeof(float4);
  float4* tab0 = (float4*)ws;  ws += (size_t)NR * sizeof(float4);
  float4* tab1 = (float4*)ws;  ws += (size_t)NR * sizeof(float4);
  float4* Sinv4 = (float4*)ws; ws += (size_t)NN * sizeof(float4);
  int* rp_adj = (int*)ws;      ws += (NN + 1) * sizeof(int);
  int* rp_ent = (int*)ws;      ws += (NN + 1) * sizeof(int);
  int* rp_rel = (int*)ws;      ws += (NN + 1) * sizeof(int);

  dim3 rg(512, 3);
  rowptr3_kernel<<<rg, 256, 0, stream>>>(adj, rp_adj, ent_adj, rp_ent, rel_adj, rp_rel);
  relpre_kernel<<<(NR * 64) / 256, 256, 0, stream>>>(rel_emb, attn_e, attn_r,
                                                     e4, tab0, tab1);
  cvt_kernel<<<(NN * HID / 8) / 256, 256, 0, stream>>>(ent_emb, enth);
  avg_tanh_kernel<<<(NN * 64) / 256, 256, 0, stream>>>(
      rp_ent, ent_adj + NT, enth, rp_rel, rel_adj + NT, rel_emb, out, C0h);
  for (int l = 0; l < 2; ++l) {
    attn_kernel<<<(NN * 64) / 256, 256, 0, stream>>>(
        out, rp_adj, adj + NT, r_index + NT, r_val, rel_emb,
        (l == 0) ? tab0 : tab1, e4, Sinv4, (l == 0) ? C0h : C1h,
        (l == 0) ? C1h : nullptr, l);
  }
}